// Round 1
// baseline (273.396 us; speedup 1.0000x reference)
//
#include <hip/hip_runtime.h>
#include <math.h>
#include <limits.h>

#define VCB 128000
#define NROW 128
#define NBINS 8192
#define NT 1024
#define BPT (NBINS / NT)   // bins per thread = 8
#define CAP 1024

__device__ __forceinline__ int binof(float x) {
    int b = (int)floorf((x + 8.0f) * 512.0f);   // width 2^-9 over [-8, 8)
    b = b < 0 ? 0 : b;
    b = b > NBINS - 1 ? NBINS - 1 : b;
    return b;
}

__device__ __forceinline__ unsigned fmono(float x) {
    unsigned b = __float_as_uint(x);
    return b ^ ((b >> 31) ? 0xFFFFFFFFu : 0x80000000u);
}
__device__ __forceinline__ float fmono_inv(unsigned m) {
    unsigned b = (m & 0x80000000u) ? (m ^ 0x80000000u) : ~m;
    return __uint_as_float(b);
}

// numpy argmax semantics: first NaN wins; else max value, first index on ties.
__device__ __forceinline__ bool better(float v1, int i1, float v2, int i2) {
    bool n1 = (v1 != v1), n2 = (v2 != v2);
    if (n1 != n2) return n1;
    if (n1) return i1 < i2;
    if (v1 != v2) return v1 > v2;
    return i1 < i2;
}

__global__ __launch_bounds__(NT) void topk_topp_sample(
    const float* __restrict__ logits, const int* __restrict__ kk,
    const float* __restrict__ pp, const float* __restrict__ noise,
    int* __restrict__ out)
{
    const int row = blockIdx.x;
    const int tid = threadIdx.x;
    const float* lrow = logits + (size_t)row * VCB;
    const float* nrow = noise  + (size_t)row * VCB;
    const float4* l4 = reinterpret_cast<const float4*>(lrow);
    const float4* n4 = reinterpret_cast<const float4*>(nrow);

    __shared__ unsigned hcnt[NBINS];
    __shared__ float    hsum[NBINS];
    __shared__ unsigned chCnt[NT];
    __shared__ float    chSum[NT];
    __shared__ float    redf[NT];      // reused: max-reduce, sortedP, argmax-reduce
    __shared__ int      redi[NT];
    __shared__ float    candK[CAP];
    __shared__ float    candP[CAP];
    __shared__ float s_rowmax, s_psP, s_cutK, s_Lcut;
    __shared__ int s_binK, s_rankK, s_binP, s_binP2, s_nK, s_nP;
    __shared__ unsigned s_pcP, s_minP2;

    const int kv = kk[row];
    const float pv = pp[row];

    for (int i = tid; i < NBINS; i += NT) { hcnt[i] = 0u; hsum[i] = 0.0f; }
    if (tid == 0) {
        s_binK = -1; s_rankK = 0; s_binP = -1; s_binP2 = NBINS;
        s_nK = 0; s_nP = 0; s_minP2 = 0xFFFFFFFFu; s_cutK = -INFINITY;
        s_pcP = 0u; s_psP = 0.0f;
    }
    __syncthreads();

    // ---- Pass A: histogram (count + sum exp(l)) and row max ----
    float lmax = -INFINITY;
    for (int i = tid; i < VCB / 4; i += NT) {
        float4 q = l4[i];
        float xs[4] = {q.x, q.y, q.z, q.w};
        #pragma unroll
        for (int c = 0; c < 4; ++c) {
            float x = xs[c];
            lmax = fmaxf(lmax, x);
            int b = binof(x);
            atomicAdd(&hcnt[b], 1u);
            atomicAdd(&hsum[b], expf(x));
        }
    }
    redf[tid] = lmax;
    __syncthreads();
    for (int s = NT / 2; s > 0; s >>= 1) {
        if (tid < s) redf[tid] = fmaxf(redf[tid], redf[tid + s]);
        __syncthreads();
    }
    if (tid == 0) s_rowmax = redf[0];

    // ---- chunk sums + Hillis-Steele inclusive scan over 1024 chunks ----
    unsigned cc = 0; float cs = 0.0f;
    #pragma unroll
    for (int j = 0; j < BPT; ++j) { cc += hcnt[tid * BPT + j]; cs += hsum[tid * BPT + j]; }
    chCnt[tid] = cc; chSum[tid] = cs;
    __syncthreads();
    for (int off = 1; off < NT; off <<= 1) {
        unsigned uc = chCnt[tid]; float uf = chSum[tid];
        unsigned ac = (tid >= off) ? chCnt[tid - off] : 0u;
        float    af = (tid >= off) ? chSum[tid - off] : 0.0f;
        __syncthreads();
        chCnt[tid] = uc + ac; chSum[tid] = uf + af;
        __syncthreads();
    }
    const float Z = chSum[NT - 1];
    const float T = (1.0f - pv) * Z;

    // ---- locate bin holding ascending rank V-k (exact) and top-p crossing bin ----
    {
        unsigned pc = (tid > 0) ? chCnt[tid - 1] : 0u;
        float ps = (tid > 0) ? chSum[tid - 1] : 0.0f;
        const unsigned rk = (unsigned)(VCB - kv);
        #pragma unroll
        for (int j = 0; j < BPT; ++j) {
            int bin = tid * BPT + j;
            unsigned c = hcnt[bin]; float s = hsum[bin];
            if (kv < VCB && c > 0u && rk >= pc && rk < pc + c) {
                s_binK = bin; s_rankK = (int)(rk - pc);
            }
            if (c > 0u && ps <= T && ps + s > T) {
                if (atomicCAS(&s_binP, -1, bin) == -1) { s_pcP = pc; s_psP = ps; }
            }
            pc += c; ps += s;
        }
    }
    __syncthreads();
    // fallback (float prefix chain can have a seam gap across chunks): serial scan
    if (tid == 0 && s_binP < 0) {
        unsigned pc = 0u; float ps = 0.0f;
        int lastb = -1; unsigned lastpc = 0u; float lastps = 0.0f;
        for (int b = 0; b < NBINS; ++b) {
            unsigned c = hcnt[b]; float s = hsum[b];
            if (c > 0u) {
                if (ps <= T && ps + s > T) { s_binP = b; s_pcP = pc; s_psP = ps; break; }
                lastb = b; lastpc = pc; lastps = ps;
            }
            pc += c; ps += s;
        }
        if (s_binP < 0) { s_binP = lastb; s_pcP = lastpc; s_psP = lastps; }
    }
    __syncthreads();
    // next nonempty bin above binP (needed if crossing lands exactly past the bin)
    {
        const int bp = s_binP;
        #pragma unroll
        for (int j = 0; j < BPT; ++j) {
            int bin = tid * BPT + j;
            if (bin > bp && hcnt[bin] > 0u) atomicMin(&s_binP2, bin);
        }
    }
    __syncthreads();

    // ---- Pass B: collect candidates of the two target bins ----
    {
        const int bK = s_binK, bP = s_binP, bP2 = s_binP2;
        for (int i = tid; i < VCB / 4; i += NT) {
            float4 q = l4[i];
            float xs[4] = {q.x, q.y, q.z, q.w};
            #pragma unroll
            for (int c = 0; c < 4; ++c) {
                float x = xs[c];
                int b = binof(x);
                if (b == bK) { int pos = atomicAdd(&s_nK, 1); if (pos < CAP) candK[pos] = x; }
                if (b == bP) { int pos = atomicAdd(&s_nP, 1); if (pos < CAP) candP[pos] = x; }
                if (b == bP2) atomicMin(&s_minP2, fmono(x));
            }
        }
    }
    __syncthreads();

    const int nK = min(s_nK, CAP), nP = min(s_nP, CAP);
    // exact top-k cutoff: candidate with ascending rank s_rankK
    if (kv < VCB && tid < nK) {
        float v = candK[tid];
        int r = 0;
        for (int j = 0; j < nK; ++j) {
            float u = candK[j];
            r += (int)((u < v) | ((u == v) & (j < tid)));
        }
        if (r == s_rankK) s_cutK = v;
    }
    // rank-sort candP ascending into redf
    if (tid < nP) {
        float v = candP[tid];
        int r = 0;
        for (int j = 0; j < nP; ++j) {
            float u = candP[j];
            r += (int)((u < v) | ((u == v) & (j < tid)));
        }
        redf[r] = v;
    }
    __syncthreads();
    if (tid == 0) {
        float cutP;
        if (nP <= 0) {
            cutP = -INFINITY;
        } else {
            float cum = s_psP; int cin = 0;
            while (cin < nP) {
                float nc = cum + expf(redf[cin]);
                if (nc <= T) { cum = nc; ++cin; } else break;
            }
            long cglob = (long)s_pcP + cin;
            if (cglob > (long)(VCB - 1)) cglob = VCB - 1;   // keep at least one token
            int local = (int)(cglob - (long)s_pcP);
            cutP = (local < nP) ? redf[local] : fmono_inv(s_minP2);
        }
        float cutK = (kv < VCB) ? s_cutK : -INFINITY;
        s_Lcut = fmaxf(cutK, cutP);
    }
    __syncthreads();

    // ---- Pass C: argmax over kept of exp(l - max)/noise, numpy NaN semantics ----
    const float Lcut = s_Lcut, rmax = s_rowmax;
    float bv = -INFINITY; int bi = INT_MAX;
    for (int i = tid; i < VCB / 4; i += NT) {
        float4 lq = l4[i];
        float4 nq = n4[i];
        float ls[4] = {lq.x, lq.y, lq.z, lq.w};
        float ns[4] = {nq.x, nq.y, nq.z, nq.w};
        #pragma unroll
        for (int c = 0; c < 4; ++c) {
            int idx = 4 * i + c;
            float prob = (ls[c] >= Lcut) ? expf(ls[c] - rmax) : 0.0f;
            float r = prob / ns[c];   // 0/noise for dropped; NaN if noise==0 & dropped
            if (better(r, idx, bv, bi)) { bv = r; bi = idx; }
        }
    }
    redf[tid] = bv; redi[tid] = bi;
    __syncthreads();
    for (int s = NT / 2; s > 0; s >>= 1) {
        if (tid < s) {
            if (better(redf[tid + s], redi[tid + s], redf[tid], redi[tid])) {
                redf[tid] = redf[tid + s]; redi[tid] = redi[tid + s];
            }
        }
        __syncthreads();
    }
    if (tid == 0) out[row] = redi[0];
}

extern "C" void kernel_launch(void* const* d_in, const int* in_sizes, int n_in,
                              void* d_out, int out_size, void* d_ws, size_t ws_size,
                              hipStream_t stream) {
    const float* logits = (const float*)d_in[0];
    const int*   k      = (const int*)d_in[1];
    const float* p      = (const float*)d_in[2];
    const float* noise  = (const float*)d_in[3];
    int* out = (int*)d_out;
    topk_topp_sample<<<dim3(NROW), dim3(NT), 0, stream>>>(logits, k, p, noise, out);
}

// Round 2
// 179.163 us; speedup vs baseline: 1.5260x; 1.5260x over previous
//
#include <hip/hip_runtime.h>
#include <math.h>
#include <limits.h>

#define V 128000
#define R 128
#define NB 8192
#define NT 1024
#define SLICES 4
#define SLICE (V / SLICES)   // 32000
#define S4 (SLICE / 4)       // 8000 float4 per slice
#define CAP 1024
#define BPT (NB / NT)        // 8 bins per thread

struct Rec {
    float rowmax;
    float Lcut;
    float T;
    float psP;
    int   binK;
    int   rankK;
    int   binP;
    int   binP2;
    unsigned pcP;
    unsigned minP2;
    int   nK;
    int   nP;
};

__device__ __forceinline__ int binof(float x) {
    int b = (int)floorf((x + 8.0f) * 512.0f);   // width 2^-9 over [-8, 8)
    b = b < 0 ? 0 : b;
    b = b > NB - 1 ? NB - 1 : b;
    return b;
}

__device__ __forceinline__ unsigned fmono(float x) {
    unsigned b = __float_as_uint(x);
    return b ^ ((b >> 31) ? 0xFFFFFFFFu : 0x80000000u);
}
__device__ __forceinline__ float fmono_inv(unsigned m) {
    unsigned b = (m & 0x80000000u) ? (m ^ 0x80000000u) : ~m;
    return __uint_as_float(b);
}

// numpy argmax semantics: first NaN wins; else max value, first index on ties.
__device__ __forceinline__ bool better(float v1, int i1, float v2, int i2) {
    bool n1 = (v1 != v1), n2 = (v2 != v2);
    if (n1 != n2) return n1;
    if (n1) return i1 < i2;
    if (v1 != v2) return v1 > v2;
    return i1 < i2;
}

// ---------------- K1: per-slice histogram (count + sum exp) + slice max ----------------
template<bool ATOMIC>
__global__ __launch_bounds__(NT) void k1_hist(
    const float* __restrict__ logits,
    unsigned* __restrict__ histCnt, float* __restrict__ histSum,
    float* __restrict__ sliceMax, unsigned* __restrict__ rowMaxMono)
{
    const int row = blockIdx.x / SLICES;
    const int sl  = blockIdx.x % SLICES;
    const int tid = threadIdx.x;
    const float4* l4 = reinterpret_cast<const float4*>(logits + (size_t)row * V) + (size_t)sl * S4;

    __shared__ unsigned hc[NB];
    __shared__ float    hs[NB];
    __shared__ float    redf[NT];

    for (int i = tid; i < NB; i += NT) { hc[i] = 0u; hs[i] = 0.0f; }
    __syncthreads();

    float lmax = -INFINITY;
    for (int i = tid; i < S4; i += NT) {
        float4 q = l4[i];
        float xs[4] = {q.x, q.y, q.z, q.w};
        #pragma unroll
        for (int c = 0; c < 4; ++c) {
            float x = xs[c];
            lmax = fmaxf(lmax, x);
            int b = binof(x);
            atomicAdd(&hc[b], 1u);
            atomicAdd(&hs[b], expf(x));
        }
    }
    redf[tid] = lmax;
    __syncthreads();
    for (int s = NT / 2; s > 0; s >>= 1) {
        if (tid < s) redf[tid] = fmaxf(redf[tid], redf[tid + s]);
        __syncthreads();
    }

    if (ATOMIC) {
        unsigned* gc = histCnt + (size_t)row * NB;
        float*    gs = histSum + (size_t)row * NB;
        for (int i = tid; i < NB; i += NT) {
            unsigned c = hc[i];
            if (c) { atomicAdd(&gc[i], c); atomicAdd(&gs[i], hs[i]); }
        }
        if (tid == 0) atomicMax(&rowMaxMono[row], fmono(redf[0]));
    } else {
        unsigned* gc = histCnt + ((size_t)sl * R + row) * NB;
        float*    gs = histSum + ((size_t)sl * R + row) * NB;
        for (int i = tid; i < NB; i += NT) { gc[i] = hc[i]; gs[i] = hs[i]; }
        if (tid == 0) sliceMax[row * SLICES + sl] = redf[0];
    }
}

// ---------------- K2a: merge + scan + locate bins, init record ----------------
template<bool ATOMIC>
__global__ __launch_bounds__(NT) void k2a_scan(
    const unsigned* __restrict__ histCnt, const float* __restrict__ histSum,
    const float* __restrict__ sliceMax, const unsigned* __restrict__ rowMaxMono,
    const int* __restrict__ kk, const float* __restrict__ pp,
    Rec* __restrict__ rec)
{
    const int row = blockIdx.x;
    const int tid = threadIdx.x;

    __shared__ unsigned hcnt[NB];
    __shared__ float    hsum[NB];
    __shared__ unsigned chCnt[NT];
    __shared__ float    chSum[NT];
    __shared__ float s_psP;
    __shared__ int s_binK, s_rankK, s_binP, s_binP2;
    __shared__ unsigned s_pcP;

    if (tid == 0) {
        s_binK = -1; s_rankK = 0; s_binP = -1; s_binP2 = NB;
        s_pcP = 0u; s_psP = 0.0f;
    }

    if (ATOMIC) {
        const unsigned* gc = histCnt + (size_t)row * NB;
        const float*    gs = histSum + (size_t)row * NB;
        for (int i = tid; i < NB; i += NT) { hcnt[i] = gc[i]; hsum[i] = gs[i]; }
    } else {
        for (int i = tid; i < NB; i += NT) {
            unsigned c = 0; float s = 0.0f;
            #pragma unroll
            for (int sl = 0; sl < SLICES; ++sl) {
                c += histCnt[((size_t)sl * R + row) * NB + i];
                s += histSum[((size_t)sl * R + row) * NB + i];
            }
            hcnt[i] = c; hsum[i] = s;
        }
    }
    __syncthreads();

    const int kv = kk[row];
    const float pv = pp[row];

    // chunk sums + Hillis-Steele inclusive scan over 1024 chunks
    unsigned cc = 0; float cs = 0.0f;
    #pragma unroll
    for (int j = 0; j < BPT; ++j) { cc += hcnt[tid * BPT + j]; cs += hsum[tid * BPT + j]; }
    chCnt[tid] = cc; chSum[tid] = cs;
    __syncthreads();
    for (int off = 1; off < NT; off <<= 1) {
        unsigned uc = chCnt[tid]; float uf = chSum[tid];
        unsigned ac = (tid >= off) ? chCnt[tid - off] : 0u;
        float    af = (tid >= off) ? chSum[tid - off] : 0.0f;
        __syncthreads();
        chCnt[tid] = uc + ac; chSum[tid] = uf + af;
        __syncthreads();
    }
    const float Z = chSum[NT - 1];
    const float T = (1.0f - pv) * Z;

    // locate bin holding ascending rank V-k (exact) and top-p crossing bin
    {
        unsigned pc = (tid > 0) ? chCnt[tid - 1] : 0u;
        float ps = (tid > 0) ? chSum[tid - 1] : 0.0f;
        const unsigned rk = (unsigned)(V - kv);
        #pragma unroll
        for (int j = 0; j < BPT; ++j) {
            int bin = tid * BPT + j;
            unsigned c = hcnt[bin]; float s = hsum[bin];
            if (kv < V && c > 0u && rk >= pc && rk < pc + c) {
                s_binK = bin; s_rankK = (int)(rk - pc);
            }
            if (c > 0u && ps <= T && ps + s > T) {
                if (atomicCAS(&s_binP, -1, bin) == -1) { s_pcP = pc; s_psP = ps; }
            }
            pc += c; ps += s;
        }
    }
    __syncthreads();
    // fallback for the float prefix seam across chunks: serial scan
    if (tid == 0 && s_binP < 0) {
        unsigned pc = 0u; float ps = 0.0f;
        int lastb = -1; unsigned lastpc = 0u; float lastps = 0.0f;
        for (int b = 0; b < NB; ++b) {
            unsigned c = hcnt[b]; float s = hsum[b];
            if (c > 0u) {
                if (ps <= T && ps + s > T) { s_binP = b; s_pcP = pc; s_psP = ps; break; }
                lastb = b; lastpc = pc; lastps = ps;
            }
            pc += c; ps += s;
        }
        if (s_binP < 0) { s_binP = lastb; s_pcP = lastpc; s_psP = lastps; }
    }
    __syncthreads();
    // next nonempty bin above binP
    {
        const int bp = s_binP;
        #pragma unroll
        for (int j = 0; j < BPT; ++j) {
            int bin = tid * BPT + j;
            if (bin > bp && hcnt[bin] > 0u) atomicMin(&s_binP2, bin);
        }
    }
    __syncthreads();

    if (tid == 0) {
        float rm;
        if (ATOMIC) {
            rm = fmono_inv(rowMaxMono[row]);
        } else {
            rm = sliceMax[row * SLICES + 0];
            #pragma unroll
            for (int sl = 1; sl < SLICES; ++sl) rm = fmaxf(rm, sliceMax[row * SLICES + sl]);
        }
        Rec rc;
        rc.rowmax = rm; rc.Lcut = -INFINITY; rc.T = T; rc.psP = s_psP;
        rc.binK = s_binK; rc.rankK = s_rankK; rc.binP = s_binP; rc.binP2 = s_binP2;
        rc.pcP = s_pcP; rc.minP2 = 0xFFFFFFFFu; rc.nK = 0; rc.nP = 0;
        rec[row] = rc;
    }
}

// ---------------- K2b: collect candidates of the target bins ----------------
__global__ __launch_bounds__(NT) void k2b_collect(
    const float* __restrict__ logits, Rec* __restrict__ rec,
    float* __restrict__ candK, float* __restrict__ candP)
{
    const int row = blockIdx.x / SLICES;
    const int sl  = blockIdx.x % SLICES;
    const int tid = threadIdx.x;
    const float4* l4 = reinterpret_cast<const float4*>(logits + (size_t)row * V) + (size_t)sl * S4;

    const int bK = rec[row].binK, bP = rec[row].binP, bP2 = rec[row].binP2;
    float* cK = candK + (size_t)row * CAP;
    float* cP = candP + (size_t)row * CAP;

    for (int i = tid; i < S4; i += NT) {
        float4 q = l4[i];
        float xs[4] = {q.x, q.y, q.z, q.w};
        #pragma unroll
        for (int c = 0; c < 4; ++c) {
            float x = xs[c];
            int b = binof(x);
            if (b == bK) { int pos = atomicAdd(&rec[row].nK, 1); if (pos < CAP) cK[pos] = x; }
            if (b == bP) { int pos = atomicAdd(&rec[row].nP, 1); if (pos < CAP) cP[pos] = x; }
            if (b == bP2) atomicMin(&rec[row].minP2, fmono(x));
        }
    }
}

// ---------------- K2c: exact cutoffs from candidates ----------------
__global__ __launch_bounds__(NT) void k2c_cutoff(
    const int* __restrict__ kk, Rec* __restrict__ rec,
    const float* __restrict__ candK, const float* __restrict__ candP)
{
    const int row = blockIdx.x;
    const int tid = threadIdx.x;

    __shared__ float lcK[CAP];
    __shared__ float lcP[CAP];
    __shared__ float sorted[CAP];
    __shared__ float s_cutK;

    if (tid == 0) s_cutK = -INFINITY;
    const int kv = kk[row];
    const Rec rc = rec[row];
    const int nK = min(rc.nK, CAP), nP = min(rc.nP, CAP);

    if (tid < nK) lcK[tid] = candK[(size_t)row * CAP + tid];
    if (tid < nP) lcP[tid] = candP[(size_t)row * CAP + tid];
    __syncthreads();

    // exact top-k cutoff: candidate with ascending rank rc.rankK
    if (kv < V && tid < nK) {
        float v = lcK[tid];
        int r = 0;
        for (int j = 0; j < nK; ++j) {
            float u = lcK[j];
            r += (int)((u < v) | ((u == v) & (j < tid)));
        }
        if (r == rc.rankK) s_cutK = v;
    }
    // rank-sort candP ascending
    if (tid < nP) {
        float v = lcP[tid];
        int r = 0;
        for (int j = 0; j < nP; ++j) {
            float u = lcP[j];
            r += (int)((u < v) | ((u == v) & (j < tid)));
        }
        sorted[r] = v;
    }
    __syncthreads();

    if (tid == 0) {
        float cutP;
        if (nP <= 0) {
            cutP = -INFINITY;
        } else {
            float cum = rc.psP; int cin = 0;
            while (cin < nP) {
                float nc = cum + expf(sorted[cin]);
                if (nc <= rc.T) { cum = nc; ++cin; } else break;
            }
            long cglob = (long)rc.pcP + cin;
            if (cglob > (long)(V - 1)) cglob = V - 1;   // keep at least one token
            int local = (int)(cglob - (long)rc.pcP);
            cutP = (local < nP) ? sorted[local] : fmono_inv(rc.minP2);
        }
        float cutK = (kv < V) ? s_cutK : -INFINITY;
        rec[row].Lcut = fmaxf(cutK, cutP);
    }
}

// ---------------- K3: per-slice argmax of exp(l - max)/noise ----------------
__global__ __launch_bounds__(NT) void k3_argmax(
    const float* __restrict__ logits, const float* __restrict__ noise,
    const Rec* __restrict__ rec, float* __restrict__ partV, int* __restrict__ partI)
{
    const int row = blockIdx.x / SLICES;
    const int sl  = blockIdx.x % SLICES;
    const int tid = threadIdx.x;
    const float4* l4 = reinterpret_cast<const float4*>(logits + (size_t)row * V) + (size_t)sl * S4;
    const float4* n4 = reinterpret_cast<const float4*>(noise  + (size_t)row * V) + (size_t)sl * S4;
    const int base = sl * SLICE;

    __shared__ float redf[NT];
    __shared__ int   redi[NT];

    const float Lcut = rec[row].Lcut, rmax = rec[row].rowmax;
    float bv = -INFINITY; int bi = INT_MAX;
    for (int i = tid; i < S4; i += NT) {
        float4 lq = l4[i];
        float4 nq = n4[i];
        float ls[4] = {lq.x, lq.y, lq.z, lq.w};
        float ns[4] = {nq.x, nq.y, nq.z, nq.w};
        #pragma unroll
        for (int c = 0; c < 4; ++c) {
            int idx = base + 4 * i + c;
            float prob = (ls[c] >= Lcut) ? expf(ls[c] - rmax) : 0.0f;
            float r = prob / ns[c];   // 0/noise for dropped; NaN if noise==0 & dropped
            if (better(r, idx, bv, bi)) { bv = r; bi = idx; }
        }
    }
    redf[tid] = bv; redi[tid] = bi;
    __syncthreads();
    for (int s = NT / 2; s > 0; s >>= 1) {
        if (tid < s) {
            if (better(redf[tid + s], redi[tid + s], redf[tid], redi[tid])) {
                redf[tid] = redf[tid + s]; redi[tid] = redi[tid + s];
            }
        }
        __syncthreads();
    }
    if (tid == 0) { partV[row * SLICES + sl] = redf[0]; partI[row * SLICES + sl] = redi[0]; }
}

// ---------------- K4: final reduce over slices ----------------
__global__ __launch_bounds__(R) void k4_final(
    const float* __restrict__ partV, const int* __restrict__ partI, int* __restrict__ out)
{
    const int row = threadIdx.x;
    float bv = partV[row * SLICES + 0]; int bi = partI[row * SLICES + 0];
    #pragma unroll
    for (int sl = 1; sl < SLICES; ++sl) {
        float v = partV[row * SLICES + sl]; int i = partI[row * SLICES + sl];
        if (better(v, i, bv, bi)) { bv = v; bi = i; }
    }
    out[row] = bi;
}

// ================= fallback: round-0 monolithic kernel (no ws) =================
__global__ __launch_bounds__(NT) void topk_topp_sample_mono(
    const float* __restrict__ logits, const int* __restrict__ kk,
    const float* __restrict__ pp, const float* __restrict__ noise,
    int* __restrict__ out)
{
    const int row = blockIdx.x;
    const int tid = threadIdx.x;
    const float4* l4 = reinterpret_cast<const float4*>(logits + (size_t)row * V);
    const float4* n4 = reinterpret_cast<const float4*>(noise  + (size_t)row * V);

    __shared__ unsigned hcnt[NB];
    __shared__ float    hsum[NB];
    __shared__ unsigned chCnt[NT];
    __shared__ float    chSum[NT];
    __shared__ float    redf[NT];
    __shared__ int      redi[NT];
    __shared__ float    candK[CAP];
    __shared__ float    candP[CAP];
    __shared__ float s_rowmax, s_psP, s_cutK, s_Lcut;
    __shared__ int s_binK, s_rankK, s_binP, s_binP2, s_nK, s_nP;
    __shared__ unsigned s_pcP, s_minP2;

    const int kv = kk[row];
    const float pv = pp[row];

    for (int i = tid; i < NB; i += NT) { hcnt[i] = 0u; hsum[i] = 0.0f; }
    if (tid == 0) {
        s_binK = -1; s_rankK = 0; s_binP = -1; s_binP2 = NB;
        s_nK = 0; s_nP = 0; s_minP2 = 0xFFFFFFFFu; s_cutK = -INFINITY;
        s_pcP = 0u; s_psP = 0.0f;
    }
    __syncthreads();

    float lmax = -INFINITY;
    for (int i = tid; i < V / 4; i += NT) {
        float4 q = l4[i];
        float xs[4] = {q.x, q.y, q.z, q.w};
        #pragma unroll
        for (int c = 0; c < 4; ++c) {
            float x = xs[c];
            lmax = fmaxf(lmax, x);
            int b = binof(x);
            atomicAdd(&hcnt[b], 1u);
            atomicAdd(&hsum[b], expf(x));
        }
    }
    redf[tid] = lmax;
    __syncthreads();
    for (int s = NT / 2; s > 0; s >>= 1) {
        if (tid < s) redf[tid] = fmaxf(redf[tid], redf[tid + s]);
        __syncthreads();
    }
    if (tid == 0) s_rowmax = redf[0];

    unsigned cc = 0; float cs = 0.0f;
    #pragma unroll
    for (int j = 0; j < BPT; ++j) { cc += hcnt[tid * BPT + j]; cs += hsum[tid * BPT + j]; }
    chCnt[tid] = cc; chSum[tid] = cs;
    __syncthreads();
    for (int off = 1; off < NT; off <<= 1) {
        unsigned uc = chCnt[tid]; float uf = chSum[tid];
        unsigned ac = (tid >= off) ? chCnt[tid - off] : 0u;
        float    af = (tid >= off) ? chSum[tid - off] : 0.0f;
        __syncthreads();
        chCnt[tid] = uc + ac; chSum[tid] = uf + af;
        __syncthreads();
    }
    const float Z = chSum[NT - 1];
    const float T = (1.0f - pv) * Z;

    {
        unsigned pc = (tid > 0) ? chCnt[tid - 1] : 0u;
        float ps = (tid > 0) ? chSum[tid - 1] : 0.0f;
        const unsigned rk = (unsigned)(V - kv);
        #pragma unroll
        for (int j = 0; j < BPT; ++j) {
            int bin = tid * BPT + j;
            unsigned c = hcnt[bin]; float s = hsum[bin];
            if (kv < V && c > 0u && rk >= pc && rk < pc + c) {
                s_binK = bin; s_rankK = (int)(rk - pc);
            }
            if (c > 0u && ps <= T && ps + s > T) {
                if (atomicCAS(&s_binP, -1, bin) == -1) { s_pcP = pc; s_psP = ps; }
            }
            pc += c; ps += s;
        }
    }
    __syncthreads();
    if (tid == 0 && s_binP < 0) {
        unsigned pc = 0u; float ps = 0.0f;
        int lastb = -1; unsigned lastpc = 0u; float lastps = 0.0f;
        for (int b = 0; b < NB; ++b) {
            unsigned c = hcnt[b]; float s = hsum[b];
            if (c > 0u) {
                if (ps <= T && ps + s > T) { s_binP = b; s_pcP = pc; s_psP = ps; break; }
                lastb = b; lastpc = pc; lastps = ps;
            }
            pc += c; ps += s;
        }
        if (s_binP < 0) { s_binP = lastb; s_pcP = lastpc; s_psP = lastps; }
    }
    __syncthreads();
    {
        const int bp = s_binP;
        #pragma unroll
        for (int j = 0; j < BPT; ++j) {
            int bin = tid * BPT + j;
            if (bin > bp && hcnt[bin] > 0u) atomicMin(&s_binP2, bin);
        }
    }
    __syncthreads();

    {
        const int bK = s_binK, bP = s_binP, bP2 = s_binP2;
        for (int i = tid; i < V / 4; i += NT) {
            float4 q = l4[i];
            float xs[4] = {q.x, q.y, q.z, q.w};
            #pragma unroll
            for (int c = 0; c < 4; ++c) {
                float x = xs[c];
                int b = binof(x);
                if (b == bK) { int pos = atomicAdd(&s_nK, 1); if (pos < CAP) candK[pos] = x; }
                if (b == bP) { int pos = atomicAdd(&s_nP, 1); if (pos < CAP) candP[pos] = x; }
                if (b == bP2) atomicMin(&s_minP2, fmono(x));
            }
        }
    }
    __syncthreads();

    const int nK = min(s_nK, CAP), nP = min(s_nP, CAP);
    if (kv < V && tid < nK) {
        float v = candK[tid];
        int r = 0;
        for (int j = 0; j < nK; ++j) {
            float u = candK[j];
            r += (int)((u < v) | ((u == v) & (j < tid)));
        }
        if (r == s_rankK) s_cutK = v;
    }
    if (tid < nP) {
        float v = candP[tid];
        int r = 0;
        for (int j = 0; j < nP; ++j) {
            float u = candP[j];
            r += (int)((u < v) | ((u == v) & (j < tid)));
        }
        redf[r] = v;
    }
    __syncthreads();
    if (tid == 0) {
        float cutP;
        if (nP <= 0) {
            cutP = -INFINITY;
        } else {
            float cum = s_psP; int cin = 0;
            while (cin < nP) {
                float nc = cum + expf(redf[cin]);
                if (nc <= T) { cum = nc; ++cin; } else break;
            }
            long cglob = (long)s_pcP + cin;
            if (cglob > (long)(V - 1)) cglob = V - 1;
            int local = (int)(cglob - (long)s_pcP);
            cutP = (local < nP) ? redf[local] : fmono_inv(s_minP2);
        }
        float cutK = (kv < V) ? s_cutK : -INFINITY;
        s_Lcut = fmaxf(cutK, cutP);
    }
    __syncthreads();

    const float Lcut = s_Lcut, rmax = s_rowmax;
    float bv = -INFINITY; int bi = INT_MAX;
    for (int i = tid; i < V / 4; i += NT) {
        float4 lq = l4[i];
        float4 nq = n4[i];
        float ls[4] = {lq.x, lq.y, lq.z, lq.w};
        float ns[4] = {nq.x, nq.y, nq.z, nq.w};
        #pragma unroll
        for (int c = 0; c < 4; ++c) {
            int idx = 4 * i + c;
            float prob = (ls[c] >= Lcut) ? expf(ls[c] - rmax) : 0.0f;
            float r = prob / ns[c];
            if (better(r, idx, bv, bi)) { bv = r; bi = idx; }
        }
    }
    redf[tid] = bv; redi[tid] = bi;
    __syncthreads();
    for (int s = NT / 2; s > 0; s >>= 1) {
        if (tid < s) {
            if (better(redf[tid + s], redi[tid + s], redf[tid], redi[tid])) {
                redf[tid] = redf[tid + s]; redi[tid] = redi[tid + s];
            }
        }
        __syncthreads();
    }
    if (tid == 0) out[row] = redi[0];
}

// ================= launch =================
static inline size_t alignup(size_t x) { return (x + 255) & ~(size_t)255; }

extern "C" void kernel_launch(void* const* d_in, const int* in_sizes, int n_in,
                              void* d_out, int out_size, void* d_ws, size_t ws_size,
                              hipStream_t stream) {
    const float* logits = (const float*)d_in[0];
    const int*   kk     = (const int*)d_in[1];
    const float* pp     = (const float*)d_in[2];
    const float* noise  = (const float*)d_in[3];
    int* out = (int*)d_out;
    char* ws = (char*)d_ws;

    // ---- non-atomic layout (deterministic, preferred) ----
    {
        size_t o = 0;
        size_t histCntOff = o; o = alignup(o + (size_t)SLICES * R * NB * 4);
        size_t histSumOff = o; o = alignup(o + (size_t)SLICES * R * NB * 4);
        size_t sliceMaxOff = o; o = alignup(o + (size_t)R * SLICES * 4);
        size_t recOff = o; o = alignup(o + (size_t)R * sizeof(Rec));
        size_t candKOff = o; o = alignup(o + (size_t)R * CAP * 4);
        size_t candPOff = o; o = alignup(o + (size_t)R * CAP * 4);
        size_t partVOff = o; o = alignup(o + (size_t)R * SLICES * 4);
        size_t partIOff = o; o = alignup(o + (size_t)R * SLICES * 4);
        if (ws_size >= o) {
            unsigned* histCnt = (unsigned*)(ws + histCntOff);
            float*    histSum = (float*)(ws + histSumOff);
            float*    sliceMax = (float*)(ws + sliceMaxOff);
            Rec*      rec = (Rec*)(ws + recOff);
            float*    candK = (float*)(ws + candKOff);
            float*    candP = (float*)(ws + candPOff);
            float*    partV = (float*)(ws + partVOff);
            int*      partI = (int*)(ws + partIOff);
            k1_hist<false><<<R * SLICES, NT, 0, stream>>>(logits, histCnt, histSum, sliceMax, nullptr);
            k2a_scan<false><<<R, NT, 0, stream>>>(histCnt, histSum, sliceMax, nullptr, kk, pp, rec);
            k2b_collect<<<R * SLICES, NT, 0, stream>>>(logits, rec, candK, candP);
            k2c_cutoff<<<R, NT, 0, stream>>>(kk, rec, candK, candP);
            k3_argmax<<<R * SLICES, NT, 0, stream>>>(logits, noise, rec, partV, partI);
            k4_final<<<1, R, 0, stream>>>(partV, partI, out);
            return;
        }
    }
    // ---- atomic-merge layout (smaller ws) ----
    {
        size_t o = 0;
        size_t histCntOff = o; o = alignup(o + (size_t)R * NB * 4);
        size_t histSumOff = o; o = alignup(o + (size_t)R * NB * 4);
        size_t rowMaxOff = o; o = alignup(o + (size_t)R * 4);
        size_t zeroBytes = o;
        size_t recOff = o; o = alignup(o + (size_t)R * sizeof(Rec));
        size_t candKOff = o; o = alignup(o + (size_t)R * CAP * 4);
        size_t candPOff = o; o = alignup(o + (size_t)R * CAP * 4);
        size_t partVOff = o; o = alignup(o + (size_t)R * SLICES * 4);
        size_t partIOff = o; o = alignup(o + (size_t)R * SLICES * 4);
        if (ws_size >= o) {
            unsigned* histCnt = (unsigned*)(ws + histCntOff);
            float*    histSum = (float*)(ws + histSumOff);
            unsigned* rowMaxMono = (unsigned*)(ws + rowMaxOff);
            Rec*      rec = (Rec*)(ws + recOff);
            float*    candK = (float*)(ws + candKOff);
            float*    candP = (float*)(ws + candPOff);
            float*    partV = (float*)(ws + partVOff);
            int*      partI = (int*)(ws + partIOff);
            hipMemsetAsync(d_ws, 0, zeroBytes, stream);
            k1_hist<true><<<R * SLICES, NT, 0, stream>>>(logits, histCnt, histSum, nullptr, rowMaxMono);
            k2a_scan<true><<<R, NT, 0, stream>>>(histCnt, histSum, nullptr, rowMaxMono, kk, pp, rec);
            k2b_collect<<<R * SLICES, NT, 0, stream>>>(logits, rec, candK, candP);
            k2c_cutoff<<<R, NT, 0, stream>>>(kk, rec, candK, candP);
            k3_argmax<<<R * SLICES, NT, 0, stream>>>(logits, noise, rec, partV, partI);
            k4_final<<<1, R, 0, stream>>>(partV, partI, out);
            return;
        }
    }
    // ---- last resort: monolithic (no ws) ----
    topk_topp_sample_mono<<<R, NT, 0, stream>>>(logits, kk, pp, noise, out);
}

// Round 3
// 112.603 us; speedup vs baseline: 2.4280x; 1.5911x over previous
//
#include <hip/hip_runtime.h>
#include <math.h>
#include <limits.h>

#define V 128000
#define R 128
#define NB 4096
#define NT 1024
#define SLICES 4
#define SLICE (V / SLICES)   // 32000
#define S4 (SLICE / 4)       // 8000 float4 per slice
#define CAP 1024
#define BPT (NB / NT)        // 4 bins per thread

typedef unsigned long long u64;

struct Rec {
    u64   Tu;        // top-p threshold, fixed-point 2^24
    u64   psPu;      // exact prefix exp-sum below binP
    float rowmax;
    float Lcut;
    int   binK;
    int   rankK;
    int   binP;
    int   binP2;
    unsigned pcP;
    unsigned minP2;
    int   nK;
    int   nP;
};

__device__ __forceinline__ int binof(float x) {
    int b = (int)floorf((x + 8.0f) * 256.0f);   // width 2^-8 over [-8, 8)
    b = b < 0 ? 0 : b;
    b = b > NB - 1 ? NB - 1 : b;
    return b;
}

// fixed-point exp: 2^24 scale, deterministic u64 accumulation.
// clamp at 14 => per-term <= 2e13, 128000 terms <= 2.6e18 < u64 max.
__device__ __forceinline__ u64 expq(float x) {
    float xc = fminf(x, 14.0f);
    return (u64)(expf(xc) * 16777216.0f);
}

__device__ __forceinline__ unsigned fmono(float x) {
    unsigned b = __float_as_uint(x);
    return b ^ ((b >> 31) ? 0xFFFFFFFFu : 0x80000000u);
}
__device__ __forceinline__ float fmono_inv(unsigned m) {
    unsigned b = (m & 0x80000000u) ? (m ^ 0x80000000u) : ~m;
    return __uint_as_float(b);
}

// numpy argmax semantics: first NaN wins; else max value, first index on ties.
__device__ __forceinline__ bool better(float v1, int i1, float v2, int i2) {
    bool n1 = (v1 != v1), n2 = (v2 != v2);
    if (n1 != n2) return n1;
    if (n1) return i1 < i2;
    if (v1 != v2) return v1 > v2;
    return i1 < i2;
}

// ---------------- K1: per-slice histogram (count u32 + exp-sum u64 fixed point) + slice max ----------------
__global__ __launch_bounds__(NT) void k1_hist(
    const float* __restrict__ logits,
    unsigned* __restrict__ histCnt, u64* __restrict__ histSum,
    float* __restrict__ sliceMax)
{
    const int row = blockIdx.x / SLICES;
    const int sl  = blockIdx.x % SLICES;
    const int tid = threadIdx.x;
    const float4* l4 = reinterpret_cast<const float4*>(logits + (size_t)row * V) + (size_t)sl * S4;

    __shared__ unsigned hc[NB];
    __shared__ u64      hs[NB];
    __shared__ float    redf[NT];

    for (int i = tid; i < NB; i += NT) { hc[i] = 0u; hs[i] = 0ull; }
    __syncthreads();

    float lmax = -INFINITY;
    for (int i = tid; i < S4; i += NT) {
        float4 q = l4[i];
        float xs[4] = {q.x, q.y, q.z, q.w};
        #pragma unroll
        for (int c = 0; c < 4; ++c) {
            float x = xs[c];
            lmax = fmaxf(lmax, x);
            int b = binof(x);
            atomicAdd(&hc[b], 1u);
            atomicAdd(&hs[b], expq(x));   // native ds_add_u64, no fp-CAS loop
        }
    }
    redf[tid] = lmax;
    __syncthreads();
    for (int s = NT / 2; s > 0; s >>= 1) {
        if (tid < s) redf[tid] = fmaxf(redf[tid], redf[tid + s]);
        __syncthreads();
    }

    unsigned* gc = histCnt + ((size_t)sl * R + row) * NB;
    u64*      gs = histSum + ((size_t)sl * R + row) * NB;
    for (int i = tid; i < NB; i += NT) { gc[i] = hc[i]; gs[i] = hs[i]; }
    if (tid == 0) sliceMax[row * SLICES + sl] = redf[0];
}

// ---------------- K2a: merge + exact u64 scan + locate bins, init record ----------------
__global__ __launch_bounds__(NT) void k2a_scan(
    const unsigned* __restrict__ histCnt, const u64* __restrict__ histSum,
    const float* __restrict__ sliceMax,
    const int* __restrict__ kk, const float* __restrict__ pp,
    Rec* __restrict__ rec)
{
    const int row = blockIdx.x;
    const int tid = threadIdx.x;

    __shared__ unsigned hcnt[NB];
    __shared__ u64      hsum[NB];
    __shared__ unsigned chCnt[NT];
    __shared__ u64      chSum[NT];
    __shared__ u64 s_psPu;
    __shared__ int s_binK, s_rankK, s_binP, s_binP2;
    __shared__ unsigned s_pcP;

    if (tid == 0) {
        s_binK = -1; s_rankK = 0; s_binP = -1; s_binP2 = NB;
        s_pcP = 0u; s_psPu = 0ull;
    }

    for (int i = tid; i < NB; i += NT) {
        unsigned c = 0; u64 s = 0ull;
        #pragma unroll
        for (int sl = 0; sl < SLICES; ++sl) {
            c += histCnt[((size_t)sl * R + row) * NB + i];
            s += histSum[((size_t)sl * R + row) * NB + i];
        }
        hcnt[i] = c; hsum[i] = s;
    }
    __syncthreads();

    const int kv = kk[row];
    const float pv = pp[row];

    // chunk sums + Hillis-Steele inclusive scan (exact integer arithmetic)
    unsigned cc = 0; u64 cs = 0ull;
    #pragma unroll
    for (int j = 0; j < BPT; ++j) { cc += hcnt[tid * BPT + j]; cs += hsum[tid * BPT + j]; }
    chCnt[tid] = cc; chSum[tid] = cs;
    __syncthreads();
    for (int off = 1; off < NT; off <<= 1) {
        unsigned uc = chCnt[tid]; u64 uf = chSum[tid];
        unsigned ac = (tid >= off) ? chCnt[tid - off] : 0u;
        u64      af = (tid >= off) ? chSum[tid - off] : 0ull;
        __syncthreads();
        chCnt[tid] = uc + ac; chSum[tid] = uf + af;
        __syncthreads();
    }
    const u64 Zu = chSum[NT - 1];
    const float omp = 1.0f - pv;
    const u64 Tu = (u64)((double)omp * (double)Zu);

    // locate bin holding ascending rank V-k (exact) and top-p crossing bin (exact u64)
    {
        unsigned pc = (tid > 0) ? chCnt[tid - 1] : 0u;
        u64 ps = (tid > 0) ? chSum[tid - 1] : 0ull;
        const unsigned rk = (unsigned)(V - kv);
        #pragma unroll
        for (int j = 0; j < BPT; ++j) {
            int bin = tid * BPT + j;
            unsigned c = hcnt[bin]; u64 s = hsum[bin];
            if (kv < V && c > 0u && rk >= pc && rk < pc + c) {
                s_binK = bin; s_rankK = (int)(rk - pc);
            }
            if (c > 0u && ps <= Tu && ps + s > Tu) {
                if (atomicCAS(&s_binP, -1, bin) == -1) { s_pcP = pc; s_psPu = ps; }
            }
            pc += c; ps += s;
        }
    }
    __syncthreads();
    // insurance fallback (integer scan is exact; should never trigger)
    if (tid == 0 && s_binP < 0) {
        unsigned pc = 0u; u64 ps = 0ull;
        int lastb = -1; unsigned lastpc = 0u; u64 lastps = 0ull;
        for (int b = 0; b < NB; ++b) {
            unsigned c = hcnt[b]; u64 s = hsum[b];
            if (c > 0u) {
                if (ps <= Tu && ps + s > Tu) { s_binP = b; s_pcP = pc; s_psPu = ps; break; }
                lastb = b; lastpc = pc; lastps = ps;
            }
            pc += c; ps += s;
        }
        if (s_binP < 0) { s_binP = lastb; s_pcP = lastpc; s_psPu = lastps; }
    }
    __syncthreads();
    // next nonempty bin above binP
    {
        const int bp = s_binP;
        #pragma unroll
        for (int j = 0; j < BPT; ++j) {
            int bin = tid * BPT + j;
            if (bin > bp && hcnt[bin] > 0u) atomicMin(&s_binP2, bin);
        }
    }
    __syncthreads();

    if (tid == 0) {
        float rm = sliceMax[row * SLICES + 0];
        #pragma unroll
        for (int sl = 1; sl < SLICES; ++sl) rm = fmaxf(rm, sliceMax[row * SLICES + sl]);
        Rec rc;
        rc.Tu = Tu; rc.psPu = s_psPu;
        rc.rowmax = rm; rc.Lcut = -INFINITY;
        rc.binK = s_binK; rc.rankK = s_rankK; rc.binP = s_binP; rc.binP2 = s_binP2;
        rc.pcP = s_pcP; rc.minP2 = 0xFFFFFFFFu; rc.nK = 0; rc.nP = 0;
        rec[row] = rc;
    }
}

// ---------------- K2b: collect candidates of the target bins ----------------
__global__ __launch_bounds__(NT) void k2b_collect(
    const float* __restrict__ logits, Rec* __restrict__ rec,
    float* __restrict__ candK, float* __restrict__ candP)
{
    const int row = blockIdx.x / SLICES;
    const int sl  = blockIdx.x % SLICES;
    const int tid = threadIdx.x;
    const float4* l4 = reinterpret_cast<const float4*>(logits + (size_t)row * V) + (size_t)sl * S4;

    const int bK = rec[row].binK, bP = rec[row].binP, bP2 = rec[row].binP2;
    float* cK = candK + (size_t)row * CAP;
    float* cP = candP + (size_t)row * CAP;

    for (int i = tid; i < S4; i += NT) {
        float4 q = l4[i];
        float xs[4] = {q.x, q.y, q.z, q.w};
        #pragma unroll
        for (int c = 0; c < 4; ++c) {
            float x = xs[c];
            int b = binof(x);
            if (b == bK) { int pos = atomicAdd(&rec[row].nK, 1); if (pos < CAP) cK[pos] = x; }
            if (b == bP) { int pos = atomicAdd(&rec[row].nP, 1); if (pos < CAP) cP[pos] = x; }
            if (b == bP2) atomicMin(&rec[row].minP2, fmono(x));
        }
    }
}

// ---------------- K2c: exact cutoffs from candidates ----------------
__global__ __launch_bounds__(NT) void k2c_cutoff(
    const int* __restrict__ kk, Rec* __restrict__ rec,
    const float* __restrict__ candK, const float* __restrict__ candP)
{
    const int row = blockIdx.x;
    const int tid = threadIdx.x;

    __shared__ float lcK[CAP];
    __shared__ float lcP[CAP];
    __shared__ float sorted[CAP];
    __shared__ float s_cutK;

    if (tid == 0) s_cutK = -INFINITY;
    const int kv = kk[row];
    const Rec rc = rec[row];
    const int nK = min(rc.nK, CAP), nP = min(rc.nP, CAP);

    if (tid < nK) lcK[tid] = candK[(size_t)row * CAP + tid];
    if (tid < nP) lcP[tid] = candP[(size_t)row * CAP + tid];
    __syncthreads();

    // exact top-k cutoff: candidate with ascending rank rc.rankK
    if (kv < V && tid < nK) {
        float v = lcK[tid];
        int r = 0;
        for (int j = 0; j < nK; ++j) {
            float u = lcK[j];
            r += (int)((u < v) | ((u == v) & (j < tid)));
        }
        if (r == rc.rankK) s_cutK = v;
    }
    // rank-sort candP ascending
    if (tid < nP) {
        float v = lcP[tid];
        int r = 0;
        for (int j = 0; j < nP; ++j) {
            float u = lcP[j];
            r += (int)((u < v) | ((u == v) & (j < tid)));
        }
        sorted[r] = v;
    }
    __syncthreads();

    if (tid == 0) {
        float cutP;
        if (nP <= 0) {
            cutP = -INFINITY;
        } else {
            // walk in the SAME fixed-point domain K1 accumulated in -> exact
            u64 cum = rc.psPu; int cin = 0;
            while (cin < nP) {
                u64 nc = cum + expq(sorted[cin]);
                if (nc <= rc.Tu) { cum = nc; ++cin; } else break;
            }
            long cglob = (long)rc.pcP + cin;
            if (cglob > (long)(V - 1)) cglob = V - 1;   // keep at least one token
            int local = (int)(cglob - (long)rc.pcP);
            cutP = (local < nP) ? sorted[local] : fmono_inv(rc.minP2);
        }
        float cutK = (kv < V) ? s_cutK : -INFINITY;
        rec[row].Lcut = fmaxf(cutK, cutP);
    }
}

// ---------------- K3: per-slice argmax of exp(l - max)/noise ----------------
__global__ __launch_bounds__(NT) void k3_argmax(
    const float* __restrict__ logits, const float* __restrict__ noise,
    const Rec* __restrict__ rec, float* __restrict__ partV, int* __restrict__ partI)
{
    const int row = blockIdx.x / SLICES;
    const int sl  = blockIdx.x % SLICES;
    const int tid = threadIdx.x;
    const float4* l4 = reinterpret_cast<const float4*>(logits + (size_t)row * V) + (size_t)sl * S4;
    const float4* n4 = reinterpret_cast<const float4*>(noise  + (size_t)row * V) + (size_t)sl * S4;
    const int base = sl * SLICE;

    __shared__ float redf[NT];
    __shared__ int   redi[NT];

    const float Lcut = rec[row].Lcut, rmax = rec[row].rowmax;
    float bv = -INFINITY; int bi = INT_MAX;
    for (int i = tid; i < S4; i += NT) {
        float4 lq = l4[i];
        float4 nq = n4[i];
        float ls[4] = {lq.x, lq.y, lq.z, lq.w};
        float ns[4] = {nq.x, nq.y, nq.z, nq.w};
        #pragma unroll
        for (int c = 0; c < 4; ++c) {
            int idx = base + 4 * i + c;
            float prob = (ls[c] >= Lcut) ? expf(ls[c] - rmax) : 0.0f;
            float r = prob / ns[c];   // 0/noise for dropped; NaN if noise==0 & dropped
            if (better(r, idx, bv, bi)) { bv = r; bi = idx; }
        }
    }
    redf[tid] = bv; redi[tid] = bi;
    __syncthreads();
    for (int s = NT / 2; s > 0; s >>= 1) {
        if (tid < s) {
            if (better(redf[tid + s], redi[tid + s], redf[tid], redi[tid])) {
                redf[tid] = redf[tid + s]; redi[tid] = redi[tid + s];
            }
        }
        __syncthreads();
    }
    if (tid == 0) { partV[row * SLICES + sl] = redf[0]; partI[row * SLICES + sl] = redi[0]; }
}

// ---------------- K4: final reduce over slices ----------------
__global__ __launch_bounds__(R) void k4_final(
    const float* __restrict__ partV, const int* __restrict__ partI, int* __restrict__ out)
{
    const int row = threadIdx.x;
    float bv = partV[row * SLICES + 0]; int bi = partI[row * SLICES + 0];
    #pragma unroll
    for (int sl = 1; sl < SLICES; ++sl) {
        float v = partV[row * SLICES + sl]; int i = partI[row * SLICES + sl];
        if (better(v, i, bv, bi)) { bv = v; bi = i; }
    }
    out[row] = bi;
}

// ================= fallback: monolithic single-kernel (only if ws too small) =================
__global__ __launch_bounds__(NT) void topk_topp_sample_mono(
    const float* __restrict__ logits, const int* __restrict__ kk,
    const float* __restrict__ pp, const float* __restrict__ noise,
    int* __restrict__ out)
{
    const int row = blockIdx.x;
    const int tid = threadIdx.x;
    const float4* l4 = reinterpret_cast<const float4*>(logits + (size_t)row * V);
    const float4* n4 = reinterpret_cast<const float4*>(noise  + (size_t)row * V);

    __shared__ unsigned hcnt[NB];
    __shared__ u64      hsum[NB];
    __shared__ unsigned chCnt[NT];
    __shared__ u64      chSum[NT];
    __shared__ float    redf[NT];
    __shared__ int      redi[NT];
    __shared__ float    candK[CAP];
    __shared__ float    candP[CAP];
    __shared__ float s_rowmax, s_cutK, s_Lcut;
    __shared__ u64 s_psPu;
    __shared__ int s_binK, s_rankK, s_binP, s_binP2, s_nK, s_nP;
    __shared__ unsigned s_pcP, s_minP2;

    const int kv = kk[row];
    const float pv = pp[row];

    for (int i = tid; i < NB; i += NT) { hcnt[i] = 0u; hsum[i] = 0ull; }
    if (tid == 0) {
        s_binK = -1; s_rankK = 0; s_binP = -1; s_binP2 = NB;
        s_nK = 0; s_nP = 0; s_minP2 = 0xFFFFFFFFu; s_cutK = -INFINITY;
        s_pcP = 0u; s_psPu = 0ull;
    }
    __syncthreads();

    float lmax = -INFINITY;
    for (int i = tid; i < V / 4; i += NT) {
        float4 q = l4[i];
        float xs[4] = {q.x, q.y, q.z, q.w};
        #pragma unroll
        for (int c = 0; c < 4; ++c) {
            float x = xs[c];
            lmax = fmaxf(lmax, x);
            int b = binof(x);
            atomicAdd(&hcnt[b], 1u);
            atomicAdd(&hsum[b], expq(x));
        }
    }
    redf[tid] = lmax;
    __syncthreads();
    for (int s = NT / 2; s > 0; s >>= 1) {
        if (tid < s) redf[tid] = fmaxf(redf[tid], redf[tid + s]);
        __syncthreads();
    }
    if (tid == 0) s_rowmax = redf[0];

    unsigned cc = 0; u64 cs = 0ull;
    #pragma unroll
    for (int j = 0; j < BPT; ++j) { cc += hcnt[tid * BPT + j]; cs += hsum[tid * BPT + j]; }
    chCnt[tid] = cc; chSum[tid] = cs;
    __syncthreads();
    for (int off = 1; off < NT; off <<= 1) {
        unsigned uc = chCnt[tid]; u64 uf = chSum[tid];
        unsigned ac = (tid >= off) ? chCnt[tid - off] : 0u;
        u64      af = (tid >= off) ? chSum[tid - off] : 0ull;
        __syncthreads();
        chCnt[tid] = uc + ac; chSum[tid] = uf + af;
        __syncthreads();
    }
    const u64 Zu = chSum[NT - 1];
    const float omp = 1.0f - pv;
    const u64 Tu = (u64)((double)omp * (double)Zu);

    {
        unsigned pc = (tid > 0) ? chCnt[tid - 1] : 0u;
        u64 ps = (tid > 0) ? chSum[tid - 1] : 0ull;
        const unsigned rk = (unsigned)(V - kv);
        #pragma unroll
        for (int j = 0; j < BPT; ++j) {
            int bin = tid * BPT + j;
            unsigned c = hcnt[bin]; u64 s = hsum[bin];
            if (kv < V && c > 0u && rk >= pc && rk < pc + c) {
                s_binK = bin; s_rankK = (int)(rk - pc);
            }
            if (c > 0u && ps <= Tu && ps + s > Tu) {
                if (atomicCAS(&s_binP, -1, bin) == -1) { s_pcP = pc; s_psPu = ps; }
            }
            pc += c; ps += s;
        }
    }
    __syncthreads();
    if (tid == 0 && s_binP < 0) {
        unsigned pc = 0u; u64 ps = 0ull;
        int lastb = -1; unsigned lastpc = 0u; u64 lastps = 0ull;
        for (int b = 0; b < NB; ++b) {
            unsigned c = hcnt[b]; u64 s = hsum[b];
            if (c > 0u) {
                if (ps <= Tu && ps + s > Tu) { s_binP = b; s_pcP = pc; s_psPu = ps; break; }
                lastb = b; lastpc = pc; lastps = ps;
            }
            pc += c; ps += s;
        }
        if (s_binP < 0) { s_binP = lastb; s_pcP = lastpc; s_psPu = lastps; }
    }
    __syncthreads();
    {
        const int bp = s_binP;
        #pragma unroll
        for (int j = 0; j < BPT; ++j) {
            int bin = tid * BPT + j;
            if (bin > bp && hcnt[bin] > 0u) atomicMin(&s_binP2, bin);
        }
    }
    __syncthreads();

    {
        const int bK = s_binK, bP = s_binP, bP2 = s_binP2;
        for (int i = tid; i < V / 4; i += NT) {
            float4 q = l4[i];
            float xs[4] = {q.x, q.y, q.z, q.w};
            #pragma unroll
            for (int c = 0; c < 4; ++c) {
                float x = xs[c];
                int b = binof(x);
                if (b == bK) { int pos = atomicAdd(&s_nK, 1); if (pos < CAP) candK[pos] = x; }
                if (b == bP) { int pos = atomicAdd(&s_nP, 1); if (pos < CAP) candP[pos] = x; }
                if (b == bP2) atomicMin(&s_minP2, fmono(x));
            }
        }
    }
    __syncthreads();

    const int nK = min(s_nK, CAP), nP = min(s_nP, CAP);
    if (kv < V && tid < nK) {
        float v = candK[tid];
        int r = 0;
        for (int j = 0; j < nK; ++j) {
            float u = candK[j];
            r += (int)((u < v) | ((u == v) & (j < tid)));
        }
        if (r == s_rankK) s_cutK = v;
    }
    if (tid < nP) {
        float v = candP[tid];
        int r = 0;
        for (int j = 0; j < nP; ++j) {
            float u = candP[j];
            r += (int)((u < v) | ((u == v) & (j < tid)));
        }
        redf[r] = v;
    }
    __syncthreads();
    if (tid == 0) {
        float cutP;
        if (nP <= 0) {
            cutP = -INFINITY;
        } else {
            u64 cum = s_psPu; int cin = 0;
            while (cin < nP) {
                u64 nc = cum + expq(redf[cin]);
                if (nc <= Tu) { cum = nc; ++cin; } else break;
            }
            long cglob = (long)s_pcP + cin;
            if (cglob > (long)(V - 1)) cglob = V - 1;
            int local = (int)(cglob - (long)s_pcP);
            cutP = (local < nP) ? redf[local] : fmono_inv(s_minP2);
        }
        float cutK = (kv < V) ? s_cutK : -INFINITY;
        s_Lcut = fmaxf(cutK, cutP);
    }
    __syncthreads();

    const float Lcut = s_Lcut, rmax = s_rowmax;
    float bv = -INFINITY; int bi = INT_MAX;
    for (int i = tid; i < V / 4; i += NT) {
        float4 lq = l4[i];
        float4 nq = n4[i];
        float ls[4] = {lq.x, lq.y, lq.z, lq.w};
        float ns[4] = {nq.x, nq.y, nq.z, nq.w};
        #pragma unroll
        for (int c = 0; c < 4; ++c) {
            int idx = 4 * i + c;
            float prob = (ls[c] >= Lcut) ? expf(ls[c] - rmax) : 0.0f;
            float r = prob / ns[c];
            if (better(r, idx, bv, bi)) { bv = r; bi = idx; }
        }
    }
    redf[tid] = bv; redi[tid] = bi;
    __syncthreads();
    for (int s = NT / 2; s > 0; s >>= 1) {
        if (tid < s) {
            if (better(redf[tid + s], redi[tid + s], redf[tid], redi[tid])) {
                redf[tid] = redf[tid + s]; redi[tid] = redi[tid + s];
            }
        }
        __syncthreads();
    }
    if (tid == 0) out[row] = redi[0];
}

// ================= launch =================
static inline size_t alignup(size_t x) { return (x + 255) & ~(size_t)255; }

extern "C" void kernel_launch(void* const* d_in, const int* in_sizes, int n_in,
                              void* d_out, int out_size, void* d_ws, size_t ws_size,
                              hipStream_t stream) {
    const float* logits = (const float*)d_in[0];
    const int*   kk     = (const int*)d_in[1];
    const float* pp     = (const float*)d_in[2];
    const float* noise  = (const float*)d_in[3];
    int* out = (int*)d_out;
    char* ws = (char*)d_ws;

    size_t o = 0;
    size_t histCntOff = o; o = alignup(o + (size_t)SLICES * R * NB * 4);
    size_t histSumOff = o; o = alignup(o + (size_t)SLICES * R * NB * 8);
    size_t sliceMaxOff = o; o = alignup(o + (size_t)R * SLICES * 4);
    size_t recOff = o; o = alignup(o + (size_t)R * sizeof(Rec));
    size_t candKOff = o; o = alignup(o + (size_t)R * CAP * 4);
    size_t candPOff = o; o = alignup(o + (size_t)R * CAP * 4);
    size_t partVOff = o; o = alignup(o + (size_t)R * SLICES * 4);
    size_t partIOff = o; o = alignup(o + (size_t)R * SLICES * 4);

    if (ws_size >= o) {
        unsigned* histCnt = (unsigned*)(ws + histCntOff);
        u64*      histSum = (u64*)(ws + histSumOff);
        float*    sliceMax = (float*)(ws + sliceMaxOff);
        Rec*      rec = (Rec*)(ws + recOff);
        float*    candK = (float*)(ws + candKOff);
        float*    candP = (float*)(ws + candPOff);
        float*    partV = (float*)(ws + partVOff);
        int*      partI = (int*)(ws + partIOff);
        k1_hist<<<R * SLICES, NT, 0, stream>>>(logits, histCnt, histSum, sliceMax);
        k2a_scan<<<R, NT, 0, stream>>>(histCnt, histSum, sliceMax, kk, pp, rec);
        k2b_collect<<<R * SLICES, NT, 0, stream>>>(logits, rec, candK, candP);
        k2c_cutoff<<<R, NT, 0, stream>>>(kk, rec, candK, candP);
        k3_argmax<<<R * SLICES, NT, 0, stream>>>(logits, noise, rec, partV, partI);
        k4_final<<<1, R, 0, stream>>>(partV, partI, out);
        return;
    }
    // last resort: monolithic (no ws)
    topk_topp_sample_mono<<<R, NT, 0, stream>>>(logits, kk, pp, noise, out);
}